// Round 4
// baseline (483.244 us; speedup 1.0000x reference)
//
#include <hip/hip_runtime.h>

#define BS 8
#define LQ 900
#define NH 8
#define NL 4
#define NP 4
#define HD 32
#define ED 256
#define LEN_V 21760

typedef __attribute__((ext_vector_type(8))) short bf16x8;
typedef __attribute__((ext_vector_type(4))) float f32x4;
typedef __attribute__((ext_vector_type(4))) float fv4;

static __device__ __forceinline__ unsigned short f2bf(float f) {
  union { float f; unsigned u; } x; x.f = f;
  unsigned r = x.u + 0x7fffu + ((x.u >> 16) & 1u);
  return (unsigned short)(r >> 16);
}
static __device__ __forceinline__ float bf2f(unsigned short s) {
  union { unsigned u; float f; } x; x.u = ((unsigned)s) << 16;
  return x.f;
}
static __device__ __forceinline__ unsigned pack2(float a, float b) {
  return (unsigned)f2bf(a) | ((unsigned)f2bf(b) << 16);
}
static __device__ __forceinline__ bf16x8 pack8(fv4 a, fv4 b) {
  union { uint4 u; bf16x8 h; } x;
  x.u.x = pack2(a.x, a.y);
  x.u.y = pack2(a.z, a.w);
  x.u.z = pack2(b.x, b.y);
  x.u.w = pack2(b.z, b.w);
  return x.h;
}

// ---------------------------------------------------------------------------
// K0: pre-swizzle w_value (256x256 fp32, [k][n]) into bf16 B-fragment chunks:
// Bsw[((kc*4+kseg)*256 + n)*8 + kin] = bf16(w[kc*32+kseg*8+kin][n])
// ---------------------------------------------------------------------------
__global__ __launch_bounds__(256) void bprep_kernel(
    const float* __restrict__ w, unsigned short* __restrict__ Bsw) {
  const int id = blockIdx.x * 256 + threadIdx.x;   // 8192 threads
  const int n = id & 255;
  const int kseg = (id >> 8) & 3;
  const int kc = id >> 10;
  const float* src = &w[(kc * 32 + kseg * 8) * 256 + n];
  float f[8];
#pragma unroll
  for (int j = 0; j < 8; j++) f[j] = src[j * 256];
  uint4 pk;
  pk.x = pack2(f[0], f[1]);
  pk.y = pack2(f[2], f[3]);
  pk.z = pack2(f[4], f[5]);
  pk.w = pack2(f[6], f[7]);
  *(uint4*)&Bsw[((kc * 4 + kseg) * 256 + n) * 8] = pk;
}

// ---------------------------------------------------------------------------
// K1: v = value @ w_value + b_value (bf16 MFMA), LDS-free, no barriers.
// Block: 256 thr = 4 waves, tile 64 rows x 256 cols; wave -> 64-col slab,
// 4x4 frags of mfma_f32_16x16x32_bf16. A loaded fp32 direct from global
// (k-contiguous), converted in-register; B loaded as pre-swizzled bf16 uint4.
// Output permuted [b][h][s][d] bf16.
// ---------------------------------------------------------------------------
__global__ __launch_bounds__(256, 3) void vproj_kernel(
    const float* __restrict__ value, const unsigned short* __restrict__ Bsw,
    const float* __restrict__ bias, unsigned short* __restrict__ vout) {
  const int t = threadIdx.x;
  const int row0 = blockIdx.x * 64;
  const int wv = t >> 6;
  const int lane = t & 63;
  const int quad = lane >> 4;
  const int nn = lane & 15;

  f32x4 acc[4][4];
#pragma unroll
  for (int i = 0; i < 4; i++)
#pragma unroll
    for (int j = 0; j < 4; j++) acc[i][j] = (f32x4)(0.f);

  const float* aptr = &value[(row0 + nn) * 256 + quad * 8];
  const unsigned short* bptr = &Bsw[(quad * 256 + wv * 64 + nn) * 8];

#pragma unroll
  for (int kc = 0; kc < 8; kc++) {
    bf16x8 af[4], bfr[4];
#pragma unroll
    for (int rt = 0; rt < 4; rt++) {
      const float* pa = aptr + rt * 16 * 256 + kc * 32;
      fv4 v0 = *(const fv4*)pa;
      fv4 v1 = *(const fv4*)(pa + 4);
      af[rt] = pack8(v0, v1);
    }
#pragma unroll
    for (int ct = 0; ct < 4; ct++)
      bfr[ct] = *(const bf16x8*)(bptr + (kc * 1024 + ct * 16) * 8);
#pragma unroll
    for (int rt = 0; rt < 4; rt++)
#pragma unroll
      for (int ct = 0; ct < 4; ct++)
        acc[rt][ct] = __builtin_amdgcn_mfma_f32_16x16x32_bf16(
            af[rt], bfr[ct], acc[rt][ct], 0, 0, 0);
  }

  // epilogue: C/D layout col=lane&15, row=quad*4+reg
#pragma unroll
  for (int ct = 0; ct < 4; ct++) {
    const int col = wv * 64 + ct * 16 + nn;
    const float bv = bias[col];
    const int h = col >> 5;
    const int d = col & 31;
#pragma unroll
    for (int rt = 0; rt < 4; rt++) {
      f32x4 f = acc[rt][ct];
#pragma unroll
      for (int reg = 0; reg < 4; reg++) {
        const int grow = row0 + rt * 16 + quad * 4 + reg;
        const int b = grow / LEN_V;
        const int s = grow - b * LEN_V;
        vout[((b * NH + h) * LEN_V + s) * HD + d] = f2bf(f[reg] + bv);
      }
    }
  }
}

// ---------------------------------------------------------------------------
// K2: OFF = query@w_off + b_off (N=256) and LOG = query@w_attn + b_attn
// (N=128), fused as N=384. 384 threads, 32 rows/block, fp32.
// ---------------------------------------------------------------------------
__global__ __launch_bounds__(384, 2) void offattn_kernel(
    const float* __restrict__ query,
    const float* __restrict__ w_off, const float* __restrict__ b_off,
    const float* __restrict__ w_attn, const float* __restrict__ b_attn,
    float* __restrict__ OFF, float* __restrict__ LOG) {
  const int t = threadIdx.x;
  const int row0 = blockIdx.x * 32;
  const int rg = t / 96;
  const int c4 = t % 96;
  const int col = c4 * 4;
  const bool isOff = col < 256;
  const float* wbase = isOff ? (w_off + col) : (w_attn + (col - 256));
  const int wstride = isOff ? 256 : 128;
  const float* bb = isOff ? (b_off + col) : (b_attn + (col - 256));
  __shared__ float a_lds[32][8];

  float4 acc[8];
#pragma unroll
  for (int r = 0; r < 8; r++) acc[r] = make_float4(0.f, 0.f, 0.f, 0.f);

  for (int k0 = 0; k0 < 256; k0 += 8) {
    __syncthreads();
    if (t < 256) a_lds[t >> 3][t & 7] = query[(row0 + (t >> 3)) * 256 + k0 + (t & 7)];
    __syncthreads();
    float4 wr[8];
#pragma unroll
    for (int k = 0; k < 8; k++)
      wr[k] = *(const float4*)&wbase[(k0 + k) * wstride];
#pragma unroll
    for (int r = 0; r < 8; r++) {
      const float* ar = &a_lds[rg * 8 + r][0];
      float4 a0 = *(const float4*)&ar[0];
      float4 a1 = *(const float4*)&ar[4];
      float4 s = acc[r];
      s.x += a0.x*wr[0].x + a0.y*wr[1].x + a0.z*wr[2].x + a0.w*wr[3].x
           + a1.x*wr[4].x + a1.y*wr[5].x + a1.z*wr[6].x + a1.w*wr[7].x;
      s.y += a0.x*wr[0].y + a0.y*wr[1].y + a0.z*wr[2].y + a0.w*wr[3].y
           + a1.x*wr[4].y + a1.y*wr[5].y + a1.z*wr[6].y + a1.w*wr[7].y;
      s.z += a0.x*wr[0].z + a0.y*wr[1].z + a0.z*wr[2].z + a0.w*wr[3].z
           + a1.x*wr[4].z + a1.y*wr[5].z + a1.z*wr[6].z + a1.w*wr[7].z;
      s.w += a0.x*wr[0].w + a0.y*wr[1].w + a0.z*wr[2].w + a0.w*wr[3].w
           + a1.x*wr[4].w + a1.y*wr[5].w + a1.z*wr[6].w + a1.w*wr[7].w;
      acc[r] = s;
    }
  }

  const float4 bv = *(const float4*)bb;
#pragma unroll
  for (int r = 0; r < 8; r++) {
    const int grow = row0 + rg * 8 + r;
    float4 o = make_float4(acc[r].x + bv.x, acc[r].y + bv.y,
                           acc[r].z + bv.z, acc[r].w + bv.w);
    if (isOff) *(float4*)&OFF[grow * 256 + col] = o;
    else       *(float4*)&LOG[grow * 128 + (col - 256)] = o;
  }
}

// ---------------------------------------------------------------------------
// K3: softmax + bilinear sampling. One block per (b, 4 queries), 256 threads.
// ---------------------------------------------------------------------------
__global__ __launch_bounds__(256, 4) void sample_kernel(
    const float* __restrict__ refp, const unsigned short* __restrict__ vp,
    const float* __restrict__ OFF, const float* __restrict__ LOG,
    float* __restrict__ RES) {
  const int t = threadIdx.x;
  const int b = blockIdx.x / (LQ / 4);
  const int q0 = (blockIdx.x % (LQ / 4)) * 4;

  __shared__ float off_lds[4][256];
  __shared__ float aw_lds[4][128];
  __shared__ float ref_lds[4][4][2];
  __shared__ int   soff[512][4];
  __shared__ float swt[512][4];

#pragma unroll
  for (int qi = 0; qi < 4; qi++)
    off_lds[qi][t] = OFF[(b * LQ + q0 + qi) * 256 + t];
  if (t < 128) {
#pragma unroll
    for (int qi = 0; qi < 4; qi++)
      aw_lds[qi][t] = LOG[(b * LQ + q0 + qi) * 128 + t];
  }
  if (t < 32) {
    const int qi = t >> 3, l = (t >> 1) & 3, xy = t & 1;
    ref_lds[qi][l][xy] = refp[((b * LQ + q0 + qi) * NL + l) * 2 + xy];
  }
  __syncthreads();

  if (t < 32) {
    const int qi = t >> 3, h = t & 7;
    float* a = &aw_lds[qi][h * 16];
    float m = a[0];
#pragma unroll
    for (int i = 1; i < 16; i++) m = fmaxf(m, a[i]);
    float e[16];
    float ssum = 0.f;
#pragma unroll
    for (int i = 0; i < 16; i++) { e[i] = __expf(a[i] - m); ssum += e[i]; }
    const float inv = 1.f / ssum;
#pragma unroll
    for (int i = 0; i < 16; i++) a[i] = e[i] * inv;
  }
  __syncthreads();

#pragma unroll
  for (int ss = 0; ss < 2; ss++) {
    const int sid = t + ss * 256;
    const int p = sid & 3, l = (sid >> 2) & 3, h = (sid >> 4) & 7, qi = sid >> 7;
    const int W = 128 >> l;
    const int base = (l == 0) ? 0 : ((l == 1) ? 16384 : ((l == 2) ? 20480 : 21504));
    const float Wf = (float)W;
    const float refx = ref_lds[qi][l][0];
    const float refy = ref_lds[qi][l][1];
    const float offx = off_lds[qi][h * 32 + l * 8 + p * 2 + 0];
    const float offy = off_lds[qi][h * 32 + l * 8 + p * 2 + 1];
    const float aw = aw_lds[qi][h * 16 + l * 4 + p];
    const float px = refx * Wf + offx - 0.5f;
    const float py = refy * Wf + offy - 0.5f;
    const float x0f = floorf(px), y0f = floorf(py);
    const float dx = px - x0f, dy = py - y0f;
    const int x0 = (int)x0f, y0 = (int)y0f;
    const int x1 = x0 + 1, y1 = y0 + 1;
    const float mx0 = (x0 >= 0 && x0 < W) ? 1.f : 0.f;
    const float mx1 = (x1 >= 0 && x1 < W) ? 1.f : 0.f;
    const float my0 = (y0 >= 0 && y0 < W) ? 1.f : 0.f;
    const float my1 = (y1 >= 0 && y1 < W) ? 1.f : 0.f;
    const int x0c = min(max(x0, 0), W - 1);
    const int x1c = min(max(x1, 0), W - 1);
    const int y0c = min(max(y0, 0), W - 1);
    const int y1c = min(max(y1, 0), W - 1);
    soff[sid][0] = (base + y0c * W + x0c) * 16;
    soff[sid][1] = (base + y0c * W + x1c) * 16;
    soff[sid][2] = (base + y1c * W + x0c) * 16;
    soff[sid][3] = (base + y1c * W + x1c) * 16;
    swt[sid][0] = (1.f - dx) * (1.f - dy) * mx0 * my0 * aw;
    swt[sid][1] = dx * (1.f - dy) * mx1 * my0 * aw;
    swt[sid][2] = (1.f - dx) * dy * mx0 * my1 * aw;
    swt[sid][3] = dx * dy * mx1 * my1 * aw;
  }
  __syncthreads();

  const int qsel = t >> 7;
  const int hh = (t >> 4) & 7;
  const int d2 = t & 15;
  const unsigned* vpu = (const unsigned*)vp + (size_t)(b * NH + hh) * (LEN_V * HD / 2);
#pragma unroll
  for (int j = 0; j < 2; j++) {
    const int qi = qsel * 2 + j;
    float r0 = 0.f, r1 = 0.f;
#pragma unroll
    for (int lp = 0; lp < 16; lp++) {
      const int sid = ((qi * 8 + hh) << 4) + lp;
      const int4 o = *(const int4*)&soff[sid][0];
      const float4 w = *(const float4*)&swt[sid][0];
      const unsigned u00 = vpu[o.x + d2];
      const unsigned u10 = vpu[o.y + d2];
      const unsigned u01 = vpu[o.z + d2];
      const unsigned u11 = vpu[o.w + d2];
      r0 += w.x * bf2f((unsigned short)(u00 & 0xffff))
          + w.y * bf2f((unsigned short)(u10 & 0xffff))
          + w.z * bf2f((unsigned short)(u01 & 0xffff))
          + w.w * bf2f((unsigned short)(u11 & 0xffff));
      r1 += w.x * bf2f((unsigned short)(u00 >> 16))
          + w.y * bf2f((unsigned short)(u10 >> 16))
          + w.z * bf2f((unsigned short)(u01 >> 16))
          + w.w * bf2f((unsigned short)(u11 >> 16));
    }
    float2 rr = make_float2(r0, r1);
    *(float2*)&RES[(b * LQ + q0 + qi) * 256 + hh * 32 + d2 * 2] = rr;
  }
}

// ---------------------------------------------------------------------------
// K4: out = RES @ w_out + b_out. fp32 register-tiled, 32 rows/block.
// ---------------------------------------------------------------------------
__global__ __launch_bounds__(256, 2) void outproj_kernel(
    const float* __restrict__ RES, const float* __restrict__ w,
    const float* __restrict__ bias, float* __restrict__ out) {
  const int t = threadIdx.x;
  const int row0 = blockIdx.x * 32;
  const int rg = t >> 6;
  const int c0 = (t & 63) << 2;
  __shared__ float a_lds[32][8];

  float4 acc[8];
#pragma unroll
  for (int r = 0; r < 8; r++) acc[r] = make_float4(0.f, 0.f, 0.f, 0.f);

  const int lr = t >> 3;
  const int lk = t & 7;
  for (int k0 = 0; k0 < 256; k0 += 8) {
    __syncthreads();
    a_lds[lr][lk] = RES[(row0 + lr) * 256 + k0 + lk];
    __syncthreads();
    float4 wr[8];
#pragma unroll
    for (int k = 0; k < 8; k++)
      wr[k] = *(const float4*)&w[(k0 + k) * 256 + c0];
#pragma unroll
    for (int r = 0; r < 8; r++) {
      const float* ar = &a_lds[rg * 8 + r][0];
      float4 a0 = *(const float4*)&ar[0];
      float4 a1 = *(const float4*)&ar[4];
      float4 s = acc[r];
      s.x += a0.x*wr[0].x + a0.y*wr[1].x + a0.z*wr[2].x + a0.w*wr[3].x
           + a1.x*wr[4].x + a1.y*wr[5].x + a1.z*wr[6].x + a1.w*wr[7].x;
      s.y += a0.x*wr[0].y + a0.y*wr[1].y + a0.z*wr[2].y + a0.w*wr[3].y
           + a1.x*wr[4].y + a1.y*wr[5].y + a1.z*wr[6].y + a1.w*wr[7].y;
      s.z += a0.x*wr[0].z + a0.y*wr[1].z + a0.z*wr[2].z + a0.w*wr[3].z
           + a1.x*wr[4].z + a1.y*wr[5].z + a1.z*wr[6].z + a1.w*wr[7].z;
      s.w += a0.x*wr[0].w + a0.y*wr[1].w + a0.z*wr[2].w + a0.w*wr[3].w
           + a1.x*wr[4].w + a1.y*wr[5].w + a1.z*wr[6].w + a1.w*wr[7].w;
      acc[r] = s;
    }
  }

  const float4 bv = *(const float4*)&bias[c0];
#pragma unroll
  for (int r = 0; r < 8; r++) {
    const int grow = row0 + rg * 8 + r;
    float4 o = make_float4(acc[r].x + bv.x, acc[r].y + bv.y,
                           acc[r].z + bv.z, acc[r].w + bv.w);
    *(float4*)&out[grow * 256 + c0] = o;
  }
}

extern "C" void kernel_launch(void* const* d_in, const int* in_sizes, int n_in,
                              void* d_out, int out_size, void* d_ws, size_t ws_size,
                              hipStream_t stream) {
  (void)in_sizes; (void)n_in; (void)out_size; (void)ws_size;
  const float* query   = (const float*)d_in[0];
  const float* refp    = (const float*)d_in[1];
  const float* value   = (const float*)d_in[2];
  const float* w_value = (const float*)d_in[3];
  const float* b_value = (const float*)d_in[4];
  const float* w_off   = (const float*)d_in[5];
  const float* b_off   = (const float*)d_in[6];
  const float* w_attn  = (const float*)d_in[7];
  const float* b_attn  = (const float*)d_in[8];
  const float* w_out   = (const float*)d_in[9];
  const float* b_out   = (const float*)d_in[10];
  float* out = (float*)d_out;

  char* ws = (char*)d_ws;
  unsigned short* vp = (unsigned short*)ws;                 // 89,128,960 B
  float* OFF = (float*)(ws + 89128960);                     // 7,372,800 B
  float* LOG = (float*)(ws + 89128960 + 7372800);           // 3,686,400 B
  float* RES = (float*)(ws + 89128960 + 7372800 + 3686400); // 7,372,800 B
  unsigned short* Bsw = (unsigned short*)(ws + 89128960 + 7372800 + 3686400 + 7372800); // 131,072 B

  bprep_kernel<<<32, 256, 0, stream>>>(w_value, Bsw);
  vproj_kernel<<<(BS * LEN_V) / 64, 256, 0, stream>>>(value, Bsw, b_value, vp);
  offattn_kernel<<<(BS * LQ) / 32, 384, 0, stream>>>(query, w_off, b_off,
                                                     w_attn, b_attn, OFF, LOG);
  sample_kernel<<<BS * (LQ / 4), 256, 0, stream>>>(refp, vp, OFF, LOG, RES);
  outproj_kernel<<<(BS * LQ) / 32, 256, 0, stream>>>(RES, w_out, b_out, out);
}

// Round 5
// 422.598 us; speedup vs baseline: 1.1435x; 1.1435x over previous
//
#include <hip/hip_runtime.h>

#define BS 8
#define LQ 900
#define NH 8
#define NL 4
#define NP 4
#define HD 32
#define ED 256
#define LEN_V 21760

typedef __attribute__((ext_vector_type(8))) short bf16x8;
typedef __attribute__((ext_vector_type(4))) float f32x4;
typedef __attribute__((ext_vector_type(4))) float fv4;

static __device__ __forceinline__ unsigned short f2bf(float f) {
  union { float f; unsigned u; } x; x.f = f;
  unsigned r = x.u + 0x7fffu + ((x.u >> 16) & 1u);
  return (unsigned short)(r >> 16);
}
static __device__ __forceinline__ float bf_lo(unsigned u) {
  union { unsigned u; float f; } x; x.u = u << 16;
  return x.f;
}
static __device__ __forceinline__ float bf_hi(unsigned u) {
  union { unsigned u; float f; } x; x.u = u & 0xffff0000u;
  return x.f;
}
static __device__ __forceinline__ unsigned pack2(float a, float b) {
  return (unsigned)f2bf(a) | ((unsigned)f2bf(b) << 16);
}

// ---------------------------------------------------------------------------
// K0: pre-swizzle w_value (256x256 fp32, [k][n]) into bf16 B-fragment chunks:
// Bsw[((kc*4+kseg)*256 + n)*8 + kin] = bf16(w[kc*32+kseg*8+kin][n])
// ---------------------------------------------------------------------------
__global__ __launch_bounds__(256) void bprep_kernel(
    const float* __restrict__ w, unsigned short* __restrict__ Bsw) {
  const int id = blockIdx.x * 256 + threadIdx.x;   // 8192 threads
  const int n = id & 255;
  const int kseg = (id >> 8) & 3;
  const int kc = id >> 10;
  const float* src = &w[(kc * 32 + kseg * 8) * 256 + n];
  float f[8];
#pragma unroll
  for (int j = 0; j < 8; j++) f[j] = src[j * 256];
  uint4 pk;
  pk.x = pack2(f[0], f[1]);
  pk.y = pack2(f[2], f[3]);
  pk.z = pack2(f[4], f[5]);
  pk.w = pack2(f[6], f[7]);
  *(uint4*)&Bsw[((kc * 4 + kseg) * 256 + n) * 8] = pk;
}

// ---------------------------------------------------------------------------
// K1: v = value @ w_value + b_value (bf16 MFMA). A staged through LDS
// (coalesced fp32 load -> bf16 pack -> 16B chunks, patterns at conflict
// floor); B fragments read directly from pre-swizzled Bsw (L2-resident).
// Block: 256 thr = 4 waves, tile 64 rows x 256 cols, wave -> 64-col slab,
// 4x4 frags of mfma_f32_16x16x32_bf16. Output permuted [b][h][s][d] bf16.
// ---------------------------------------------------------------------------
__global__ __launch_bounds__(256, 4) void vproj_kernel(
    const float* __restrict__ value, const unsigned short* __restrict__ Bsw,
    const float* __restrict__ bias, unsigned short* __restrict__ vout) {
  const int t = threadIdx.x;
  const int row0 = blockIdx.x * 64;
  const int wv = t >> 6;
  const int lane = t & 63;
  const int quad = lane >> 4;
  const int nn = lane & 15;

  __shared__ unsigned short a_lds[4 * 64 * 8];   // [kseg][row][8] 16B chunks, 4 KB

  f32x4 acc[4][4];
#pragma unroll
  for (int i = 0; i < 4; i++)
#pragma unroll
    for (int j = 0; j < 4; j++) acc[i][j] = (f32x4)(0.f);

  const int arow = t >> 2;        // 0..63
  const int akseg = t & 3;        // 0..3
  const unsigned short* bptr = &Bsw[(quad * 256 + wv * 64 + nn) * 8];

  for (int kc = 0; kc < 8; kc++) {
    __syncthreads();
    {
      const float* pa = &value[(row0 + arow) * 256 + kc * 32 + akseg * 8];
      fv4 v0 = __builtin_nontemporal_load((const fv4*)pa);
      fv4 v1 = __builtin_nontemporal_load((const fv4*)(pa + 4));
      uint4 pk;
      pk.x = pack2(v0.x, v0.y);
      pk.y = pack2(v0.z, v0.w);
      pk.z = pack2(v1.x, v1.y);
      pk.w = pack2(v1.z, v1.w);
      *(uint4*)&a_lds[(akseg * 64 + arow) * 8] = pk;
    }
    __syncthreads();

    bf16x8 af[4], bfr[4];
#pragma unroll
    for (int ct = 0; ct < 4; ct++)
      bfr[ct] = *(const bf16x8*)(bptr + (kc * 1024 + ct * 16) * 8);
#pragma unroll
    for (int rt = 0; rt < 4; rt++)
      af[rt] = *(const bf16x8*)&a_lds[(quad * 64 + rt * 16 + nn) * 8];
#pragma unroll
    for (int rt = 0; rt < 4; rt++)
#pragma unroll
      for (int ct = 0; ct < 4; ct++)
        acc[rt][ct] = __builtin_amdgcn_mfma_f32_16x16x32_bf16(
            af[rt], bfr[ct], acc[rt][ct], 0, 0, 0);
  }

  // epilogue: C/D layout col=lane&15, row=quad*4+reg. row0 % LEN_V aligned
  // (LEN_V = 64*340), so b is block-uniform.
  const int bb = row0 / LEN_V;
  const int s0 = row0 - bb * LEN_V;
#pragma unroll
  for (int ct = 0; ct < 4; ct++) {
    const int col = wv * 64 + ct * 16 + nn;
    const float bv = bias[col];
    const int h = col >> 5;
    const int d = col & 31;
    unsigned short* vb = &vout[((bb * NH + h) * LEN_V + s0) * HD + d];
#pragma unroll
    for (int rt = 0; rt < 4; rt++) {
      f32x4 f = acc[rt][ct];
#pragma unroll
      for (int reg = 0; reg < 4; reg++) {
        const int s = rt * 16 + quad * 4 + reg;
        vb[s * HD] = f2bf(f[reg] + bv);
      }
    }
  }
}

// ---------------------------------------------------------------------------
// K2: OFF = query@w_off + b_off (N=256) and LOG = query@w_attn + b_attn
// (N=128), fused as N=384. 384 threads, 32 rows/block, fp32.
// ---------------------------------------------------------------------------
__global__ __launch_bounds__(384, 2) void offattn_kernel(
    const float* __restrict__ query,
    const float* __restrict__ w_off, const float* __restrict__ b_off,
    const float* __restrict__ w_attn, const float* __restrict__ b_attn,
    float* __restrict__ OFF, float* __restrict__ LOG) {
  const int t = threadIdx.x;
  const int row0 = blockIdx.x * 32;
  const int rg = t / 96;
  const int c4 = t % 96;
  const int col = c4 * 4;
  const bool isOff = col < 256;
  const float* wbase = isOff ? (w_off + col) : (w_attn + (col - 256));
  const int wstride = isOff ? 256 : 128;
  const float* bb = isOff ? (b_off + col) : (b_attn + (col - 256));
  __shared__ float a_lds[32][8];

  float4 acc[8];
#pragma unroll
  for (int r = 0; r < 8; r++) acc[r] = make_float4(0.f, 0.f, 0.f, 0.f);

  for (int k0 = 0; k0 < 256; k0 += 8) {
    __syncthreads();
    if (t < 256) a_lds[t >> 3][t & 7] = query[(row0 + (t >> 3)) * 256 + k0 + (t & 7)];
    __syncthreads();
    float4 wr[8];
#pragma unroll
    for (int k = 0; k < 8; k++)
      wr[k] = *(const float4*)&wbase[(k0 + k) * wstride];
#pragma unroll
    for (int r = 0; r < 8; r++) {
      const float* ar = &a_lds[rg * 8 + r][0];
      float4 a0 = *(const float4*)&ar[0];
      float4 a1 = *(const float4*)&ar[4];
      float4 s = acc[r];
      s.x += a0.x*wr[0].x + a0.y*wr[1].x + a0.z*wr[2].x + a0.w*wr[3].x
           + a1.x*wr[4].x + a1.y*wr[5].x + a1.z*wr[6].x + a1.w*wr[7].x;
      s.y += a0.x*wr[0].y + a0.y*wr[1].y + a0.z*wr[2].y + a0.w*wr[3].y
           + a1.x*wr[4].y + a1.y*wr[5].y + a1.z*wr[6].y + a1.w*wr[7].y;
      s.z += a0.x*wr[0].z + a0.y*wr[1].z + a0.z*wr[2].z + a0.w*wr[3].z
           + a1.x*wr[4].z + a1.y*wr[5].z + a1.z*wr[6].z + a1.w*wr[7].z;
      s.w += a0.x*wr[0].w + a0.y*wr[1].w + a0.z*wr[2].w + a0.w*wr[3].w
           + a1.x*wr[4].w + a1.y*wr[5].w + a1.z*wr[6].w + a1.w*wr[7].w;
      acc[r] = s;
    }
  }

  const float4 bv = *(const float4*)bb;
#pragma unroll
  for (int r = 0; r < 8; r++) {
    const int grow = row0 + rg * 8 + r;
    float4 o = make_float4(acc[r].x + bv.x, acc[r].y + bv.y,
                           acc[r].z + bv.z, acc[r].w + bv.w);
    if (isOff) *(float4*)&OFF[grow * 256 + col] = o;
    else       *(float4*)&LOG[grow * 128 + (col - 256)] = o;
  }
}

// ---------------------------------------------------------------------------
// K3: softmax + bilinear sampling. One block per (b, 4 queries), 256 threads.
// Phase B: 512 (qi,h,l,p) sets -> corner uint2-offsets + aw-folded weights.
// Phase C: thread=(qi, head, dim-quad): 64 uint2 gathers (4 bf16 each).
// ---------------------------------------------------------------------------
__global__ __launch_bounds__(256, 6) void sample_kernel(
    const float* __restrict__ refp, const unsigned short* __restrict__ vp,
    const float* __restrict__ OFF, const float* __restrict__ LOG,
    float* __restrict__ RES) {
  const int t = threadIdx.x;
  const int b = blockIdx.x / (LQ / 4);
  const int q0 = (blockIdx.x % (LQ / 4)) * 4;

  __shared__ float off_lds[4][256];
  __shared__ float aw_lds[4][128];
  __shared__ float ref_lds[4][4][2];
  __shared__ int   soff[512][4];   // uint2-offsets of 4 corners
  __shared__ float swt[512][4];    // aw-folded corner weights

#pragma unroll
  for (int qi = 0; qi < 4; qi++)
    off_lds[qi][t] = OFF[(b * LQ + q0 + qi) * 256 + t];
  if (t < 128) {
#pragma unroll
    for (int qi = 0; qi < 4; qi++)
      aw_lds[qi][t] = LOG[(b * LQ + q0 + qi) * 128 + t];
  }
  if (t < 32) {
    const int qi = t >> 3, l = (t >> 1) & 3, xy = t & 1;
    ref_lds[qi][l][xy] = refp[((b * LQ + q0 + qi) * NL + l) * 2 + xy];
  }
  __syncthreads();

  if (t < 32) {
    const int qi = t >> 3, h = t & 7;
    float* a = &aw_lds[qi][h * 16];
    float m = a[0];
#pragma unroll
    for (int i = 1; i < 16; i++) m = fmaxf(m, a[i]);
    float e[16];
    float ssum = 0.f;
#pragma unroll
    for (int i = 0; i < 16; i++) { e[i] = __expf(a[i] - m); ssum += e[i]; }
    const float inv = 1.f / ssum;
#pragma unroll
    for (int i = 0; i < 16; i++) a[i] = e[i] * inv;
  }
  __syncthreads();

#pragma unroll
  for (int ss = 0; ss < 2; ss++) {
    const int sid = t + ss * 256;
    const int p = sid & 3, l = (sid >> 2) & 3, h = (sid >> 4) & 7, qi = sid >> 7;
    const int W = 128 >> l;
    const int base = (l == 0) ? 0 : ((l == 1) ? 16384 : ((l == 2) ? 20480 : 21504));
    const float Wf = (float)W;
    const float refx = ref_lds[qi][l][0];
    const float refy = ref_lds[qi][l][1];
    const float offx = off_lds[qi][h * 32 + l * 8 + p * 2 + 0];
    const float offy = off_lds[qi][h * 32 + l * 8 + p * 2 + 1];
    const float aw = aw_lds[qi][h * 16 + l * 4 + p];
    const float px = refx * Wf + offx - 0.5f;
    const float py = refy * Wf + offy - 0.5f;
    const float x0f = floorf(px), y0f = floorf(py);
    const float dx = px - x0f, dy = py - y0f;
    const int x0 = (int)x0f, y0 = (int)y0f;
    const int x1 = x0 + 1, y1 = y0 + 1;
    const float mx0 = (x0 >= 0 && x0 < W) ? 1.f : 0.f;
    const float mx1 = (x1 >= 0 && x1 < W) ? 1.f : 0.f;
    const float my0 = (y0 >= 0 && y0 < W) ? 1.f : 0.f;
    const float my1 = (y1 >= 0 && y1 < W) ? 1.f : 0.f;
    const int x0c = min(max(x0, 0), W - 1);
    const int x1c = min(max(x1, 0), W - 1);
    const int y0c = min(max(y0, 0), W - 1);
    const int y1c = min(max(y1, 0), W - 1);
    soff[sid][0] = (base + y0c * W + x0c) * 8;   // uint2 units (32 bf16 = 8 uint2)
    soff[sid][1] = (base + y0c * W + x1c) * 8;
    soff[sid][2] = (base + y1c * W + x0c) * 8;
    soff[sid][3] = (base + y1c * W + x1c) * 8;
    swt[sid][0] = (1.f - dx) * (1.f - dy) * mx0 * my0 * aw;
    swt[sid][1] = dx * (1.f - dy) * mx1 * my0 * aw;
    swt[sid][2] = (1.f - dx) * dy * mx0 * my1 * aw;
    swt[sid][3] = dx * dy * mx1 * my1 * aw;
  }
  __syncthreads();

  // ---- phase C: thread = (qi, head, dim-quad) ----
  const int qi = t >> 6;            // wave-uniform
  const int hh = (t >> 3) & 7;
  const int d4 = t & 7;             // 4 dims: d4*4 .. d4*4+3
  const uint2* vpu2 = (const uint2*)vp + (size_t)(b * NH + hh) * (LEN_V * HD / 4);
  float r0 = 0.f, r1 = 0.f, r2 = 0.f, r3 = 0.f;
  const int sbase = (qi * 8 + hh) << 4;
#pragma unroll 4
  for (int lp = 0; lp < 16; lp++) {
    const int sid = sbase + lp;
    const int4 o = *(const int4*)&soff[sid][0];
    const float4 w = *(const float4*)&swt[sid][0];
    const uint2 u00 = vpu2[o.x + d4];
    const uint2 u10 = vpu2[o.y + d4];
    const uint2 u01 = vpu2[o.z + d4];
    const uint2 u11 = vpu2[o.w + d4];
    r0 += w.x * bf_lo(u00.x) + w.y * bf_lo(u10.x) + w.z * bf_lo(u01.x) + w.w * bf_lo(u11.x);
    r1 += w.x * bf_hi(u00.x) + w.y * bf_hi(u10.x) + w.z * bf_hi(u01.x) + w.w * bf_hi(u11.x);
    r2 += w.x * bf_lo(u00.y) + w.y * bf_lo(u10.y) + w.z * bf_lo(u01.y) + w.w * bf_lo(u11.y);
    r3 += w.x * bf_hi(u00.y) + w.y * bf_hi(u10.y) + w.z * bf_hi(u01.y) + w.w * bf_hi(u11.y);
  }
  float4 rr = make_float4(r0, r1, r2, r3);
  *(float4*)&RES[(b * LQ + q0 + qi) * 256 + hh * 32 + d4 * 4] = rr;
}

// ---------------------------------------------------------------------------
// K4: out = RES @ w_out + b_out. fp32 register-tiled, 32 rows/block.
// ---------------------------------------------------------------------------
__global__ __launch_bounds__(256, 2) void outproj_kernel(
    const float* __restrict__ RES, const float* __restrict__ w,
    const float* __restrict__ bias, float* __restrict__ out) {
  const int t = threadIdx.x;
  const int row0 = blockIdx.x * 32;
  const int rg = t >> 6;
  const int c0 = (t & 63) << 2;
  __shared__ float a_lds[32][8];

  float4 acc[8];
#pragma unroll
  for (int r = 0; r < 8; r++) acc[r] = make_float4(0.f, 0.f, 0.f, 0.f);

  const int lr = t >> 3;
  const int lk = t & 7;
  for (int k0 = 0; k0 < 256; k0 += 8) {
    __syncthreads();
    a_lds[lr][lk] = RES[(row0 + lr) * 256 + k0 + lk];
    __syncthreads();
    float4 wr[8];
#pragma unroll
    for (int k = 0; k < 8; k++)
      wr[k] = *(const float4*)&w[(k0 + k) * 256 + c0];
#pragma unroll
    for (int r = 0; r < 8; r++) {
      const float* ar = &a_lds[rg * 8 + r][0];
      float4 a0 = *(const float4*)&ar[0];
      float4 a1 = *(const float4*)&ar[4];
      float4 s = acc[r];
      s.x += a0.x*wr[0].x + a0.y*wr[1].x + a0.z*wr[2].x + a0.w*wr[3].x
           + a1.x*wr[4].x + a1.y*wr[5].x + a1.z*wr[6].x + a1.w*wr[7].x;
      s.y += a0.x*wr[0].y + a0.y*wr[1].y + a0.z*wr[2].y + a0.w*wr[3].y
           + a1.x*wr[4].y + a1.y*wr[5].y + a1.z*wr[6].y + a1.w*wr[7].y;
      s.z += a0.x*wr[0].z + a0.y*wr[1].z + a0.z*wr[2].z + a0.w*wr[3].z
           + a1.x*wr[4].z + a1.y*wr[5].z + a1.z*wr[6].z + a1.w*wr[7].z;
      s.w += a0.x*wr[0].w + a0.y*wr[1].w + a0.z*wr[2].w + a0.w*wr[3].w
           + a1.x*wr[4].w + a1.y*wr[5].w + a1.z*wr[6].w + a1.w*wr[7].w;
      acc[r] = s;
    }
  }

  const float4 bv = *(const float4*)&bias[c0];
#pragma unroll
  for (int r = 0; r < 8; r++) {
    const int grow = row0 + rg * 8 + r;
    float4 o = make_float4(acc[r].x + bv.x, acc[r].y + bv.y,
                           acc[r].z + bv.z, acc[r].w + bv.w);
    *(float4*)&out[grow * 256 + c0] = o;
  }
}

extern "C" void kernel_launch(void* const* d_in, const int* in_sizes, int n_in,
                              void* d_out, int out_size, void* d_ws, size_t ws_size,
                              hipStream_t stream) {
  (void)in_sizes; (void)n_in; (void)out_size; (void)ws_size;
  const float* query   = (const float*)d_in[0];
  const float* refp    = (const float*)d_in[1];
  const float* value   = (const float*)d_in[2];
  const float* w_value = (const float*)d_in[3];
  const float* b_value = (const float*)d_in[4];
  const float* w_off   = (const float*)d_in[5];
  const float* b_off   = (const float*)d_in[6];
  const float* w_attn  = (const float*)d_in[7];
  const float* b_attn  = (const float*)d_in[8];
  const float* w_out   = (const float*)d_in[9];
  const float* b_out   = (const float*)d_in[10];
  float* out = (float*)d_out;

  char* ws = (char*)d_ws;
  unsigned short* vp = (unsigned short*)ws;                 // 89,128,960 B
  float* OFF = (float*)(ws + 89128960);                     // 7,372,800 B
  float* LOG = (float*)(ws + 89128960 + 7372800);           // 3,686,400 B
  float* RES = (float*)(ws + 89128960 + 7372800 + 3686400); // 7,372,800 B
  unsigned short* Bsw = (unsigned short*)(ws + 89128960 + 7372800 + 3686400 + 7372800); // 131,072 B

  bprep_kernel<<<32, 256, 0, stream>>>(w_value, Bsw);
  vproj_kernel<<<(BS * LEN_V) / 64, 256, 0, stream>>>(value, Bsw, b_value, vp);
  offattn_kernel<<<(BS * LQ) / 32, 384, 0, stream>>>(query, w_off, b_off,
                                                     w_attn, b_attn, OFF, LOG);
  sample_kernel<<<BS * (LQ / 4), 256, 0, stream>>>(refp, vp, OFF, LOG, RES);
  outproj_kernel<<<(BS * LQ) / 32, 256, 0, stream>>>(RES, w_out, b_out, out);
}